// Round 6
// baseline (416.320 us; speedup 1.0000x reference)
//
#include <hip/hip_runtime.h>

// BinaryLinear: y = x @ sign(W)^T + sign(b)
// R9: R8's register read-ahead with the spill fixed. R8's +16MB WRITE_SIZE
// = scratch spill (acc 128 + frags 96 + 8 VGPR of 64b pointers + temps >
// 256 unified budget). Fix: (1) global staging = SGPR uniform base + ONE
// shared 32-bit voffset (saves ~7 VGPR); (2) LDS reads = per-lane base +
// ds_read offset:mi*1024 immediates, ring term = 1 uniform v_add/step
// (saves ~8 VGPR). Schedule identical to R8 (race-audited):
//   stage(j+3) -> vmcnt(8) -> lgkm(0) -> barrier -> reads(j+1) -> MFMA(j)
// Predicted: WRITE 192->176MB (spill gone), gemm 168 -> ~95us,
// MfmaUtil -> ~60%. If ~150us with clean traffic: overlap refuted ->
// pivot A-frags to direct-from-L2 next round.

typedef __attribute__((ext_vector_type(4))) int   i32x4;
typedef __attribute__((ext_vector_type(8))) short short8;
typedef __attribute__((ext_vector_type(4))) float f32x4;

constexpr int M = 8192;
constexpr int N = 4096;
constexpr int K = 4096;

// ---- gemm geometry ----
constexpr int BM = 256, BN = 256, BK = 64;
constexpr int NTILES = K / BK;          // 64
constexpr int TILE_A = BM * BK;         // 16 KiB
constexpr int TILE_B = BN * BK;         // 16 KiB
constexpr int BUFSZ  = TILE_A + TILE_B; // 32 KiB
constexpr int RING   = 4;               // 128 KiB LDS

__device__ __forceinline__ void load_lds16(const void* g, void* l) {
    __builtin_amdgcn_global_load_lds(
        (const __attribute__((address_space(1))) unsigned int*)g,
        (__attribute__((address_space(3))) unsigned int*)l, 16, 0, 0);
}

// ---------------- fused prep (unchanged) ----------------
// blocks [0, M): prep_x block-per-row. blocks [M, M+WB): prep_w grid-stride.
constexpr int WB  = 1024;
constexpr int WCH = N * K / 8;     // uint2 chunks (8 i8 each) = 2M

__global__ __launch_bounds__(256) void prep_fused(
    const float* __restrict__ X, const float* __restrict__ W,
    signed char* __restrict__ Xq, signed char* __restrict__ Wq,
    float* __restrict__ Scale) {
    __shared__ float wmax[4];
    const int t = threadIdx.x;

    if (blockIdx.x < M) {
        const int row = blockIdx.x;
        const float4* xr = reinterpret_cast<const float4*>(X + (size_t)row * K);
        float4 v[4];
        float mx = 0.f;
#pragma unroll
        for (int i = 0; i < 4; ++i) {
            v[i] = xr[t + i * 256];
            mx = fmaxf(mx, fmaxf(fmaxf(fabsf(v[i].x), fabsf(v[i].y)),
                                 fmaxf(fabsf(v[i].z), fabsf(v[i].w))));
        }
#pragma unroll
        for (int off = 32; off > 0; off >>= 1)
            mx = fmaxf(mx, __shfl_down(mx, off));
        if ((t & 63) == 0) wmax[t >> 6] = mx;
        __syncthreads();
        float rmax = fmaxf(fmaxf(wmax[0], wmax[1]), fmaxf(wmax[2], wmax[3]));
        rmax = fmaxf(rmax, 1e-20f);
        const float inv = 127.f / rmax;
        if (t == 0) Scale[row] = rmax * (1.f / 127.f);

        unsigned int* out = reinterpret_cast<unsigned int*>(Xq + (size_t)row * K);
#pragma unroll
        for (int i = 0; i < 4; ++i) {
            int q0 = (int)rintf(v[i].x * inv);
            int q1 = (int)rintf(v[i].y * inv);
            int q2 = (int)rintf(v[i].z * inv);
            int q3 = (int)rintf(v[i].w * inv);
            unsigned int p = (q0 & 255) | ((q1 & 255) << 8) |
                             ((q2 & 255) << 16) | ((unsigned)(q3 & 255) << 24);
            out[t + i * 256] = p;
        }
    } else {
        const float4* W4 = reinterpret_cast<const float4*>(W);
        uint2* O = reinterpret_cast<uint2*>(Wq);
        auto sg = [](float f) -> unsigned int { return (f >= 0.f) ? 1u : 0xFFu; };
        size_t idx = (size_t)(blockIdx.x - M) * 256 + t;
        const size_t stride = (size_t)WB * 256;
        for (size_t c = idx; c < (size_t)WCH; c += stride) {
            float4 a = W4[c * 2], b = W4[c * 2 + 1];
            uint2 o;
            o.x = sg(a.x) | (sg(a.y) << 8) | (sg(a.z) << 16) | (sg(a.w) << 24);
            o.y = sg(b.x) | (sg(b.y) << 8) | (sg(b.z) << 16) | (sg(b.w) << 24);
            O[c] = o;
        }
    }
}

// ---------------- read-ahead pipelined 256^2 i8 GEMM (low-VGPR) ----------
struct GemmCtx {
    const signed char* Abase;   // Aq + m0*K   (block-uniform -> SGPR)
    const signed char* Bbase;   // Bq + n0*K   (block-uniform -> SGPR)
    int voff;                   // srow*K + cg (per-lane, shared by 4 streams)
    signed char* lbase;         // stage dest base (wave-uniform)
    int aoff;                   // (wm*128+rl)*BK + cq16          (per-lane)
    int boff;                   // TILE_A + (wn*64+rl)*BK + cq16  (per-lane)
};

struct Frags { i32x4 b[4]; i32x4 a[8]; };   // 48 VGPRs

__device__ __forceinline__ void stage_full(const GemmCtx& c, int t) {
    signed char* d = c.lbase + (t & (RING - 1)) * BUFSZ;
    const size_t ko = (size_t)t * BK;            // uniform
    load_lds16(c.Abase + ko + c.voff, d);
    load_lds16(c.Abase + (size_t)128 * K + ko + c.voff, d + 8192);
    load_lds16(c.Bbase + ko + c.voff, d + TILE_A);
    load_lds16(c.Bbase + (size_t)128 * K + ko + c.voff, d + TILE_A + 8192);
}

__device__ __forceinline__ void read_frags(const GemmCtx& c,
                                           const signed char* smem, int t,
                                           Frags& f) {
    const signed char* base = smem + (t & (RING - 1)) * BUFSZ;  // uniform add
#pragma unroll
    for (int ni = 0; ni < 4; ++ni)
        f.b[ni] = *reinterpret_cast<const i32x4*>(base + c.boff + ni * 1024);
#pragma unroll
    for (int mi = 0; mi < 8; ++mi)
        f.a[mi] = *reinterpret_cast<const i32x4*>(base + c.aoff + mi * 1024);
}

__device__ __forceinline__ void do_mfma(const Frags& f, i32x4 (&acc)[8][4]) {
    __builtin_amdgcn_s_setprio(1);
#pragma unroll
    for (int mi = 0; mi < 8; ++mi)
#pragma unroll
        for (int ni = 0; ni < 4; ++ni)
            acc[mi][ni] = __builtin_amdgcn_mfma_i32_16x16x64_i8(
                f.a[mi], f.b[ni], acc[mi][ni], 0, 0, 0);
    __builtin_amdgcn_s_setprio(0);
}

// One K-step: consume `cur` (frags of tile j), prefetch tile j+1 into `nxt`.
template <int VM, bool STAGE, bool RDNEXT, bool BAR>
__device__ __forceinline__ void kstep(
    const GemmCtx& c, const signed char* smem, int j,
    Frags& cur, Frags& nxt, i32x4 (&acc)[8][4]) {
    if constexpr (STAGE) stage_full(c, j + 3);
    if constexpr (VM >= 0)
        asm volatile("s_waitcnt vmcnt(%0)" :: "i"(VM) : "memory");
    if constexpr (BAR) {
        asm volatile("s_waitcnt lgkmcnt(0)" ::: "memory");
        __builtin_amdgcn_s_barrier();
        asm volatile("" ::: "memory");
    }
    if constexpr (RDNEXT) read_frags(c, smem, j + 1, nxt);
    __builtin_amdgcn_sched_barrier(0);   // keep reads above the MFMA cluster
    do_mfma(cur, acc);
}

__global__ __launch_bounds__(512, 2) void gemm_i8_p(
    const signed char* __restrict__ Aq, const signed char* __restrict__ Bq,
    const float* __restrict__ Scale, const float* __restrict__ Bias,
    float* __restrict__ OUT) {
    __shared__ signed char smem[RING * BUFSZ];  // 128 KiB

    const int tid  = threadIdx.x;
    const int lane = tid & 63;
    const int w    = tid >> 6;   // 0..7
    const int wm   = w >> 2;     // 0..1 (128-row strip)
    const int wn   = w & 3;      // 0..3 (64-col strip)
    const int rl   = lane & 15;
    // T2 swizzle: chunk' = (lane>>4) ^ ((rl>>1)&3)
    const int cq16 = (((lane >> 4) ^ ((rl >> 1) & 3)) << 4);

    // XCD-aware block swizzle (512 blocks, 512 % 8 == 0 -> bijective)
    const int wg  = blockIdx.x;
    const int lin = (wg & 7) * 64 + (wg >> 3);
    const int n0  = (lin & 15) * BN;
    const int m0  = (lin >> 4) * BM;

    // staging: linear LDS dest (row = tid/4 [+128], chunk = tid&3),
    // global chunk = linear chunk ^ swizzle(row) (same involution as reads)
    const int srow = tid >> 2;                       // 0..127
    const int cg   = ((tid & 3) ^ ((srow >> 1) & 3)) * 16;

    GemmCtx c;
    c.Abase = Aq + (size_t)m0 * K;
    c.Bbase = Bq + (size_t)n0 * K;
    c.voff  = srow * K + cg;
    c.lbase = smem + w * 1024;                       // wave-uniform
    c.aoff  = (wm * 128 + rl) * BK + cq16;
    c.boff  = TILE_A + (wn * 64 + rl) * BK + cq16;

    i32x4 acc[8][4];
#pragma unroll
    for (int mi = 0; mi < 8; ++mi)
#pragma unroll
        for (int ni = 0; ni < 4; ++ni)
            acc[mi][ni] = (i32x4){0, 0, 0, 0};

    // prologue: 3 tiles in flight; tile 0 landed; read its frags
    stage_full(c, 0); stage_full(c, 1); stage_full(c, 2);
    asm volatile("s_waitcnt vmcnt(8)" ::: "memory");
    __builtin_amdgcn_s_barrier();
    asm volatile("" ::: "memory");
    Frags fA, fB;
    read_frags(c, smem, 0, fA);

    // steady: iters 0..59 (stages 3..62), then explicit tail
    for (int j = 0; j < NTILES - 4; j += 2) {
        kstep<8, true, true, true>(c, smem, j,     fA, fB, acc);
        kstep<8, true, true, true>(c, smem, j + 1, fB, fA, acc);
    }
    kstep<8, true,  true,  true >(c, smem, NTILES - 4, fA, fB, acc); // j=60: stage 63
    kstep<4, false, true,  true >(c, smem, NTILES - 3, fB, fA, acc); // j=61
    kstep<0, false, true,  true >(c, smem, NTILES - 2, fA, fB, acc); // j=62
    kstep<-1, false, false, false>(c, smem, NTILES - 1, fB, fA, acc); // j=63

    // epilogue: C/D layout col=lane&15, row=(lane>>4)*4+reg
#pragma unroll
    for (int ni = 0; ni < 4; ++ni) {
        const int gcol = n0 + wn * 64 + ni * 16 + rl;
        const float sb = (Bias[gcol] >= 0.f) ? 1.f : -1.f;
#pragma unroll
        for (int mi = 0; mi < 8; ++mi) {
            const int growb = m0 + wm * 128 + mi * 16 + (lane >> 4) * 4;
            const float4 sc = *reinterpret_cast<const float4*>(&Scale[growb]);
            OUT[(size_t)(growb + 0) * N + gcol] = (float)acc[mi][ni][0] * sc.x + sb;
            OUT[(size_t)(growb + 1) * N + gcol] = (float)acc[mi][ni][1] * sc.y + sb;
            OUT[(size_t)(growb + 2) * N + gcol] = (float)acc[mi][ni][2] * sc.z + sb;
            OUT[(size_t)(growb + 3) * N + gcol] = (float)acc[mi][ni][3] * sc.w + sb;
        }
    }
}

// ---------------- fallback (R1 kernel): used only if ws_size is too small ----
constexpr int MT   = 128;
constexpr int NTF  = 128;
constexpr int LDSS = 40;
constexpr int KTB  = 32;
__device__ __forceinline__ unsigned short f2b(float f) {
    unsigned int u = __builtin_bit_cast(unsigned int, f);
    u += 0x7FFFu + ((u >> 16) & 1u);
    return (unsigned short)(u >> 16);
}
__global__ __launch_bounds__(256) void binlin_fallback(
    const float* __restrict__ X, const float* __restrict__ W,
    const float* __restrict__ B, float* __restrict__ OUT) {
    __shared__ unsigned short As[MT][LDSS];
    __shared__ unsigned short Bs[NTF][LDSS];
    const int tid  = threadIdx.x;
    const int lane = tid & 63;
    const int wave = tid >> 6;
    const int wm   = wave >> 1;
    const int wn   = wave & 1;
    const int m0 = blockIdx.y * MT;
    const int n0 = blockIdx.x * NTF;
    const int rl = lane & 15;
    const int kq = (lane >> 4) * 8;
    f32x4 acc[4][4];
#pragma unroll
    for (int mi = 0; mi < 4; ++mi)
#pragma unroll
        for (int ni = 0; ni < 4; ++ni)
            acc[mi][ni] = (f32x4){0.f, 0.f, 0.f, 0.f};
    for (int k0 = 0; k0 < K; k0 += KTB) {
#pragma unroll
        for (int it = 0; it < 4; ++it) {
            int g = tid + it * 256, row = g >> 3, c4 = (g & 7) << 2;
            float4 v = *reinterpret_cast<const float4*>(&X[(size_t)(m0 + row) * K + k0 + c4]);
            ushort4 h;
            h.x = f2b(v.x); h.y = f2b(v.y); h.z = f2b(v.z); h.w = f2b(v.w);
            *reinterpret_cast<ushort4*>(&As[row][c4]) = h;
        }
#pragma unroll
        for (int it = 0; it < 4; ++it) {
            int g = tid + it * 256, row = g >> 3, c4 = (g & 7) << 2;
            float4 v = *reinterpret_cast<const float4*>(&W[(size_t)(n0 + row) * K + k0 + c4]);
            ushort4 h;
            h.x = (v.x >= 0.f) ? 0x3F80u : 0xBF80u;
            h.y = (v.y >= 0.f) ? 0x3F80u : 0xBF80u;
            h.z = (v.z >= 0.f) ? 0x3F80u : 0xBF80u;
            h.w = (v.w >= 0.f) ? 0x3F80u : 0xBF80u;
            *reinterpret_cast<ushort4*>(&Bs[row][c4]) = h;
        }
        __syncthreads();
        short8 a[4], b[4];
#pragma unroll
        for (int mi = 0; mi < 4; ++mi)
            a[mi] = *reinterpret_cast<const short8*>(&As[wm * 64 + mi * 16 + rl][kq]);
#pragma unroll
        for (int ni = 0; ni < 4; ++ni)
            b[ni] = *reinterpret_cast<const short8*>(&Bs[wn * 64 + ni * 16 + rl][kq]);
#pragma unroll
        for (int mi = 0; mi < 4; ++mi)
#pragma unroll
            for (int ni = 0; ni < 4; ++ni)
                acc[mi][ni] = __builtin_amdgcn_mfma_f32_16x16x32_bf16(
                    a[mi], b[ni], acc[mi][ni], 0, 0, 0);
        __syncthreads();
    }
#pragma unroll
    for (int ni = 0; ni < 4; ++ni) {
        int gcol = n0 + wn * 64 + ni * 16 + rl;
        float sb = (B[gcol] >= 0.f) ? 1.f : -1.f;
#pragma unroll
        for (int mi = 0; mi < 4; ++mi) {
            int growb = m0 + wm * 64 + mi * 16 + (lane >> 4) * 4;
#pragma unroll
            for (int r = 0; r < 4; ++r)
                OUT[(size_t)(growb + r) * N + gcol] = acc[mi][ni][r] + sb;
        }
    }
}

extern "C" void kernel_launch(void* const* d_in, const int* in_sizes, int n_in,
                              void* d_out, int out_size, void* d_ws, size_t ws_size,
                              hipStream_t stream) {
    const float* x  = (const float*)d_in[0];
    const float* w  = (const float*)d_in[1];
    const float* b  = (const float*)d_in[2];
    float* out      = (float*)d_out;

    // ws layout: Xq [M*K i8] | Wq [N*K i8] | Scale [M f32]
    const size_t need = (size_t)M * K + (size_t)N * K + (size_t)M * sizeof(float);
    if (ws_size >= need) {
        signed char* Xq = (signed char*)d_ws;
        signed char* Wq = Xq + (size_t)M * K;
        float* Scale    = (float*)(Wq + (size_t)N * K);

        prep_fused<<<dim3(M + WB), dim3(256), 0, stream>>>(x, w, Xq, Wq, Scale);
        gemm_i8_p<<<dim3((M / BM) * (N / BN)), dim3(512), 0, stream>>>(
            Xq, Wq, Scale, b, out);
    } else {
        dim3 grid(N / NTF, M / MT);
        binlin_fallback<<<grid, dim3(256), 0, stream>>>(x, w, b, out);
    }
}

// Round 7
// 402.454 us; speedup vs baseline: 1.0345x; 1.0345x over previous
//
#include <hip/hip_runtime.h>

// BinaryLinear: y = x @ sign(W)^T + sign(b)
// R10: manual-lgkm schedule. R9 failed because the compiler, unable to see
// our asm lgkm(0), re-inserts its own lgkmcnt(0) AFTER the new ds_reads and
// before the MFMA cluster (single HW counter -> drains the new reads too,
// re-serializing LDS port (1152cy) with MFMA (1306cy) = measured 2944cy).
// Fix: fragment reads are inline-asm ds_read_b128 (compiler inserts NO
// waits); exactly one lgkm(0) per step AFTER the MFMA cluster; rule-#18
// sched_barrier(0) fences. Step: reads(j+1) | MFMA(j) | stage(j+4) |
// vmcnt(8) | lgkm(0) | barrier.  (ring-4, depth-3, cross-wave audit in
// comments below.)
// Predicted: gemm 157 -> 80-100us, MfmaUtil 38 -> 55-70%. If >=140us with
// clean counters: source-level overlap refuted -> cut LDS bytes next.

typedef __attribute__((ext_vector_type(4))) int   i32x4;
typedef __attribute__((ext_vector_type(8))) short short8;
typedef __attribute__((ext_vector_type(4))) float f32x4;

constexpr int M = 8192;
constexpr int N = 4096;
constexpr int K = 4096;

// ---- gemm geometry ----
constexpr int BM = 256, BN = 256, BK = 64;
constexpr int NTILES = K / BK;          // 64
constexpr int TILE_A = BM * BK;         // 16 KiB
constexpr int TILE_B = BN * BK;         // 16 KiB
constexpr int BUFSZ  = TILE_A + TILE_B; // 32 KiB
constexpr int RING   = 4;               // 128 KiB LDS

__device__ __forceinline__ void load_lds16(const void* g, void* l) {
    __builtin_amdgcn_global_load_lds(
        (const __attribute__((address_space(1))) unsigned int*)g,
        (__attribute__((address_space(3))) unsigned int*)l, 16, 0, 0);
}

// ---------------- fused prep (unchanged from R6) ----------------
constexpr int WB  = 1024;
constexpr int WCH = N * K / 8;     // uint2 chunks (8 i8 each) = 2M

__global__ __launch_bounds__(256) void prep_fused(
    const float* __restrict__ X, const float* __restrict__ W,
    signed char* __restrict__ Xq, signed char* __restrict__ Wq,
    float* __restrict__ Scale) {
    __shared__ float wmax[4];
    const int t = threadIdx.x;

    if (blockIdx.x < M) {
        const int row = blockIdx.x;
        const float4* xr = reinterpret_cast<const float4*>(X + (size_t)row * K);
        float4 v[4];
        float mx = 0.f;
#pragma unroll
        for (int i = 0; i < 4; ++i) {
            v[i] = xr[t + i * 256];
            mx = fmaxf(mx, fmaxf(fmaxf(fabsf(v[i].x), fabsf(v[i].y)),
                                 fmaxf(fabsf(v[i].z), fabsf(v[i].w))));
        }
#pragma unroll
        for (int off = 32; off > 0; off >>= 1)
            mx = fmaxf(mx, __shfl_down(mx, off));
        if ((t & 63) == 0) wmax[t >> 6] = mx;
        __syncthreads();
        float rmax = fmaxf(fmaxf(wmax[0], wmax[1]), fmaxf(wmax[2], wmax[3]));
        rmax = fmaxf(rmax, 1e-20f);
        const float inv = 127.f / rmax;
        if (t == 0) Scale[row] = rmax * (1.f / 127.f);

        unsigned int* out = reinterpret_cast<unsigned int*>(Xq + (size_t)row * K);
#pragma unroll
        for (int i = 0; i < 4; ++i) {
            int q0 = (int)rintf(v[i].x * inv);
            int q1 = (int)rintf(v[i].y * inv);
            int q2 = (int)rintf(v[i].z * inv);
            int q3 = (int)rintf(v[i].w * inv);
            unsigned int p = (q0 & 255) | ((q1 & 255) << 8) |
                             ((q2 & 255) << 16) | ((unsigned)(q3 & 255) << 24);
            out[t + i * 256] = p;
        }
    } else {
        const float4* W4 = reinterpret_cast<const float4*>(W);
        uint2* O = reinterpret_cast<uint2*>(Wq);
        auto sg = [](float f) -> unsigned int { return (f >= 0.f) ? 1u : 0xFFu; };
        size_t idx = (size_t)(blockIdx.x - M) * 256 + t;
        const size_t stride = (size_t)WB * 256;
        for (size_t c = idx; c < (size_t)WCH; c += stride) {
            float4 a = W4[c * 2], b = W4[c * 2 + 1];
            uint2 o;
            o.x = sg(a.x) | (sg(a.y) << 8) | (sg(a.z) << 16) | (sg(a.w) << 24);
            o.y = sg(b.x) | (sg(b.y) << 8) | (sg(b.z) << 16) | (sg(b.w) << 24);
            O[c] = o;
        }
    }
}

// ---------------- manual-lgkm pipelined 256^2 i8 GEMM ----------------
struct GemmCtx {
    const signed char* Abase;   // Aq + m0*K (SGPR)
    const signed char* Bbase;   // Bq + n0*K (SGPR)
    int voff;                   // srow*K + cg (per-lane, shared by 4 streams)
    signed char* lbase;         // stage dest base (wave-uniform)
    unsigned baseA;             // LDS byte addr of A frag row, ring slot 0
    unsigned baseB;             // LDS byte addr of B frag row, ring slot 0
};

struct Frags { i32x4 b[4]; i32x4 a[8]; };   // 48 VGPRs

__device__ __forceinline__ void stage_full(const GemmCtx& c, int t) {
    signed char* d = c.lbase + (t & (RING - 1)) * BUFSZ;
    const size_t ko = (size_t)t * BK;            // uniform
    load_lds16(c.Abase + ko + c.voff, d);
    load_lds16(c.Abase + (size_t)128 * K + ko + c.voff, d + 8192);
    load_lds16(c.Bbase + ko + c.voff, d + TILE_A);
    load_lds16(c.Bbase + (size_t)128 * K + ko + c.voff, d + TILE_A + 8192);
}

// 12 ds_read_b128 with compile-time offsets; the compiler tracks NO lgkm
// for these — all waiting is our explicit lgkm(0) per step (rule #18).
__device__ __forceinline__ void read_frags_asm(unsigned aA, unsigned aB,
                                               Frags& f) {
    asm volatile(
        "ds_read_b128 %0, %12 offset:0\n\t"
        "ds_read_b128 %1, %12 offset:1024\n\t"
        "ds_read_b128 %2, %12 offset:2048\n\t"
        "ds_read_b128 %3, %12 offset:3072\n\t"
        "ds_read_b128 %4, %13 offset:0\n\t"
        "ds_read_b128 %5, %13 offset:1024\n\t"
        "ds_read_b128 %6, %13 offset:2048\n\t"
        "ds_read_b128 %7, %13 offset:3072\n\t"
        "ds_read_b128 %8, %13 offset:4096\n\t"
        "ds_read_b128 %9, %13 offset:5120\n\t"
        "ds_read_b128 %10, %13 offset:6144\n\t"
        "ds_read_b128 %11, %13 offset:7168"
        : "=&v"(f.b[0]), "=&v"(f.b[1]), "=&v"(f.b[2]), "=&v"(f.b[3]),
          "=&v"(f.a[0]), "=&v"(f.a[1]), "=&v"(f.a[2]), "=&v"(f.a[3]),
          "=&v"(f.a[4]), "=&v"(f.a[5]), "=&v"(f.a[6]), "=&v"(f.a[7])
        : "v"(aB), "v"(aA));
}

__device__ __forceinline__ void do_mfma(const Frags& f, i32x4 (&acc)[8][4]) {
    __builtin_amdgcn_s_setprio(1);
#pragma unroll
    for (int mi = 0; mi < 8; ++mi)
#pragma unroll
        for (int ni = 0; ni < 4; ++ni)
            acc[mi][ni] = __builtin_amdgcn_mfma_i32_16x16x64_i8(
                f.a[mi], f.b[ni], acc[mi][ni], 0, 0, 0);
    __builtin_amdgcn_s_setprio(0);
}

// Step j: reads(j+1) -> [fence] -> MFMA(j) -> stage(j+4) -> vmcnt(VM) ->
// lgkm(0) -> [fence] -> barrier.
// Safety: stage(j+4) writes buf j&3; frags(j) reads were lgkm(0)-drained
// before barrier(j-1) (all waves) -> WAR safe. vmcnt(8) retires tile j+2
// before barrier(j), which precedes reads(j+2) in step j+1 -> cross-wave
// RAW safe (per-wave counter + barrier ordering).
template <int VM, bool STAGE, bool RDNEXT, bool BAR>
__device__ __forceinline__ void kstep(
    const GemmCtx& c, int j, Frags& cur, Frags& nxt, i32x4 (&acc)[8][4]) {
    if constexpr (RDNEXT) {
        const unsigned ring = (unsigned)(((j + 1) & (RING - 1)) * BUFSZ);
        read_frags_asm(c.baseA + ring, c.baseB + ring, nxt);
    }
    __builtin_amdgcn_sched_barrier(0);   // keep reads above the MFMA cluster
    do_mfma(cur, acc);
    if constexpr (STAGE) stage_full(c, j + 4);
    if constexpr (VM >= 0)
        asm volatile("s_waitcnt vmcnt(%0)" :: "i"(VM) : "memory");
    asm volatile("s_waitcnt lgkmcnt(0)" ::: "memory");
    __builtin_amdgcn_sched_barrier(0);   // rule #18: no MFMA hoist past lgkm
    if constexpr (BAR) __builtin_amdgcn_s_barrier();
}

__global__ __launch_bounds__(512, 2) void gemm_i8_p(
    const signed char* __restrict__ Aq, const signed char* __restrict__ Bq,
    const float* __restrict__ Scale, const float* __restrict__ Bias,
    float* __restrict__ OUT) {
    __shared__ signed char smem[RING * BUFSZ];  // 128 KiB

    const int tid  = threadIdx.x;
    const int lane = tid & 63;
    const int w    = tid >> 6;   // 0..7
    const int wm   = w >> 2;     // 0..1 (128-row strip)
    const int wn   = w & 3;      // 0..3 (64-col strip)
    const int rl   = lane & 15;
    // T2 swizzle: chunk' = (lane>>4) ^ ((rl>>1)&3); constant per lane since
    // (row>>1)&3 == (rl>>1)&3 for rows mi*16+rl.
    const int cq16 = (((lane >> 4) ^ ((rl >> 1) & 3)) << 4);

    // XCD-aware block swizzle (512 blocks, 512 % 8 == 0 -> bijective)
    const int wg  = blockIdx.x;
    const int lin = (wg & 7) * 64 + (wg >> 3);
    const int n0  = (lin & 15) * BN;
    const int m0  = (lin >> 4) * BM;

    // staging: linear LDS dest (row = tid/4 [+128], chunk = tid&3),
    // global chunk = linear chunk ^ swizzle(row) (same involution as reads)
    const int srow = tid >> 2;                       // 0..127
    const int cg   = ((tid & 3) ^ ((srow >> 1) & 3)) * 16;

    GemmCtx c;
    c.Abase = Aq + (size_t)m0 * K;
    c.Bbase = Bq + (size_t)n0 * K;
    c.voff  = srow * K + cg;
    c.lbase = smem + w * 1024;                       // wave-uniform
    const unsigned lds0 = (unsigned)(unsigned long long)&smem[0];
    c.baseA = lds0 + (unsigned)((wm * 128 + rl) * BK + cq16);
    c.baseB = lds0 + (unsigned)(TILE_A + (wn * 64 + rl) * BK + cq16);

    i32x4 acc[8][4];
#pragma unroll
    for (int mi = 0; mi < 8; ++mi)
#pragma unroll
        for (int ni = 0; ni < 4; ++ni)
            acc[mi][ni] = (i32x4){0, 0, 0, 0};

    // prologue: stage 4 tiles; retire 0,1; double handshake; frags(0)
    stage_full(c, 0); stage_full(c, 1); stage_full(c, 2); stage_full(c, 3);
    asm volatile("s_waitcnt vmcnt(8)" ::: "memory");
    __builtin_amdgcn_s_barrier();
    Frags fA, fB;
    read_frags_asm(c.baseA, c.baseB, fA);
    asm volatile("s_waitcnt lgkmcnt(0)" ::: "memory");
    __builtin_amdgcn_sched_barrier(0);
    __builtin_amdgcn_s_barrier();

    // steady: j = 0..59 stage tiles 4..63; vmcnt(8) retires tile j+2
    for (int j = 0; j < NTILES - 4; j += 2) {
        kstep<8, true, true, true>(c, j,     fA, fB, acc);
        kstep<8, true, true, true>(c, j + 1, fB, fA, acc);
    }
    kstep<4,  false, true,  true >(c, NTILES - 4, fA, fB, acc); // j=60: retire 62
    kstep<0,  false, true,  true >(c, NTILES - 3, fB, fA, acc); // j=61: retire 63
    kstep<-1, false, true,  false>(c, NTILES - 2, fA, fB, acc); // j=62: reads 63
    kstep<-1, false, false, false>(c, NTILES - 1, fB, fA, acc); // j=63

    // epilogue: C/D layout col=lane&15, row=(lane>>4)*4+reg
#pragma unroll
    for (int ni = 0; ni < 4; ++ni) {
        const int gcol = n0 + wn * 64 + ni * 16 + rl;
        const float sb = (Bias[gcol] >= 0.f) ? 1.f : -1.f;
#pragma unroll
        for (int mi = 0; mi < 8; ++mi) {
            const int growb = m0 + wm * 128 + mi * 16 + (lane >> 4) * 4;
            const float4 sc = *reinterpret_cast<const float4*>(&Scale[growb]);
            OUT[(size_t)(growb + 0) * N + gcol] = (float)acc[mi][ni][0] * sc.x + sb;
            OUT[(size_t)(growb + 1) * N + gcol] = (float)acc[mi][ni][1] * sc.y + sb;
            OUT[(size_t)(growb + 2) * N + gcol] = (float)acc[mi][ni][2] * sc.z + sb;
            OUT[(size_t)(growb + 3) * N + gcol] = (float)acc[mi][ni][3] * sc.w + sb;
        }
    }
}

// ---------------- fallback (R1 kernel): used only if ws_size is too small ----
constexpr int MT   = 128;
constexpr int NTF  = 128;
constexpr int LDSS = 40;
constexpr int KTB  = 32;
__device__ __forceinline__ unsigned short f2b(float f) {
    unsigned int u = __builtin_bit_cast(unsigned int, f);
    u += 0x7FFFu + ((u >> 16) & 1u);
    return (unsigned short)(u >> 16);
}
__global__ __launch_bounds__(256) void binlin_fallback(
    const float* __restrict__ X, const float* __restrict__ W,
    const float* __restrict__ B, float* __restrict__ OUT) {
    __shared__ unsigned short As[MT][LDSS];
    __shared__ unsigned short Bs[NTF][LDSS];
    const int tid  = threadIdx.x;
    const int lane = tid & 63;
    const int wave = tid >> 6;
    const int wm   = wave >> 1;
    const int wn   = wave & 1;
    const int m0 = blockIdx.y * MT;
    const int n0 = blockIdx.x * NTF;
    const int rl = lane & 15;
    const int kq = (lane >> 4) * 8;
    f32x4 acc[4][4];
#pragma unroll
    for (int mi = 0; mi < 4; ++mi)
#pragma unroll
        for (int ni = 0; ni < 4; ++ni)
            acc[mi][ni] = (f32x4){0.f, 0.f, 0.f, 0.f};
    for (int k0 = 0; k0 < K; k0 += KTB) {
#pragma unroll
        for (int it = 0; it < 4; ++it) {
            int g = tid + it * 256, row = g >> 3, c4 = (g & 7) << 2;
            float4 v = *reinterpret_cast<const float4*>(&X[(size_t)(m0 + row) * K + k0 + c4]);
            ushort4 h;
            h.x = f2b(v.x); h.y = f2b(v.y); h.z = f2b(v.z); h.w = f2b(v.w);
            *reinterpret_cast<ushort4*>(&As[row][c4]) = h;
        }
#pragma unroll
        for (int it = 0; it < 4; ++it) {
            int g = tid + it * 256, row = g >> 3, c4 = (g & 7) << 2;
            float4 v = *reinterpret_cast<const float4*>(&W[(size_t)(n0 + row) * K + k0 + c4]);
            ushort4 h;
            h.x = (v.x >= 0.f) ? 0x3F80u : 0xBF80u;
            h.y = (v.y >= 0.f) ? 0x3F80u : 0xBF80u;
            h.z = (v.z >= 0.f) ? 0x3F80u : 0xBF80u;
            h.w = (v.w >= 0.f) ? 0x3F80u : 0xBF80u;
            *reinterpret_cast<ushort4*>(&Bs[row][c4]) = h;
        }
        __syncthreads();
        short8 a[4], b[4];
#pragma unroll
        for (int mi = 0; mi < 4; ++mi)
            a[mi] = *reinterpret_cast<const short8*>(&As[wm * 64 + mi * 16 + rl][kq]);
#pragma unroll
        for (int ni = 0; ni < 4; ++ni)
            b[ni] = *reinterpret_cast<const short8*>(&Bs[wn * 64 + ni * 16 + rl][kq]);
#pragma unroll
        for (int mi = 0; mi < 4; ++mi)
#pragma unroll
            for (int ni = 0; ni < 4; ++ni)
                acc[mi][ni] = __builtin_amdgcn_mfma_f32_16x16x32_bf16(
                    a[mi], b[ni], acc[mi][ni], 0, 0, 0);
        __syncthreads();
    }
#pragma unroll
    for (int ni = 0; ni < 4; ++ni) {
        int gcol = n0 + wn * 64 + ni * 16 + rl;
        float sb = (B[gcol] >= 0.f) ? 1.f : -1.f;
#pragma unroll
        for (int mi = 0; mi < 4; ++mi) {
            int growb = m0 + wm * 64 + mi * 16 + (lane >> 4) * 4;
#pragma unroll
            for (int r = 0; r < 4; ++r)
                OUT[(size_t)(growb + r) * N + gcol] = acc[mi][ni][r] + sb;
        }
    }
}

extern "C" void kernel_launch(void* const* d_in, const int* in_sizes, int n_in,
                              void* d_out, int out_size, void* d_ws, size_t ws_size,
                              hipStream_t stream) {
    const float* x  = (const float*)d_in[0];
    const float* w  = (const float*)d_in[1];
    const float* b  = (const float*)d_in[2];
    float* out      = (float*)d_out;

    // ws layout: Xq [M*K i8] | Wq [N*K i8] | Scale [M f32]
    const size_t need = (size_t)M * K + (size_t)N * K + (size_t)M * sizeof(float);
    if (ws_size >= need) {
        signed char* Xq = (signed char*)d_ws;
        signed char* Wq = Xq + (size_t)M * K;
        float* Scale    = (float*)(Wq + (size_t)N * K);

        prep_fused<<<dim3(M + WB), dim3(256), 0, stream>>>(x, w, Xq, Wq, Scale);
        gemm_i8_p<<<dim3((M / BM) * (N / BN)), dim3(512), 0, stream>>>(
            Xq, Wq, Scale, b, out);
    } else {
        dim3 grid(N / NTF, M / MT);
        binlin_fallback<<<grid, dim3(256), 0, stream>>>(x, w, b, out);
    }
}